// Round 1
// 835.613 us; speedup vs baseline: 1.0039x; 1.0039x over previous
//
#include <hip/hip_runtime.h>
#include <math.h>

// Problem: per-object 3-layer MLP (grouped GEMV).
//   N_OBJ=2048, IN_DIM=128, MID_DIM=256, OUT_DIM=1
// ~770 MB of weights streamed exactly once -> memory-bound, roofline ~122 us
// at 6.3 TB/s achievable.
//
// Key change vs previous version: row-per-THREAD (1 KB-strided, uncoalesced,
// ~920 GB/s) -> row-per-WAVE with lane-contiguous float4 loads + shuffle
// reduction, so every global load instruction covers a contiguous 1 KB.

#define N_OBJ   2048
#define IN_DIM  128
#define MID_DIM 256

__global__ __launch_bounds__(256, 8) void mlp_grouped_kernel(
    const float* __restrict__ x,   // [O, 128]
    const float* __restrict__ W1,  // [O, 256, 128]
    const float* __restrict__ b1,  // [O, 256]
    const float* __restrict__ W2,  // [O, 256, 256]
    const float* __restrict__ b2,  // [O, 256]
    const float* __restrict__ W3,  // [O, 1, 256]
    const float* __restrict__ b3,  // [O, 1]
    float* __restrict__ out)       // [O]
{
    const int o = blockIdx.x;
    const int t = threadIdx.x;
    const int w = t >> 6;   // wave id 0..3
    const int l = t & 63;   // lane id

    __shared__ __align__(16) float s_y1[MID_DIM];
    __shared__ __align__(16) float s_y2[MID_DIM];

    // ----- Layer 1: y1[row] = dot(x, W1[o,row,:]) + b1[o,row]  (NO activation)
    // 2 rows per iteration: lanes 0..31 -> row 2i, lanes 32..63 -> row 2i+1.
    // Each load instruction covers a contiguous 1 KB (2 rows x 512 B).
    {
        const int sub = l & 31;   // float4 slot within the row
        const int rh  = l >> 5;   // which of the two rows
        const float4 xv = *(const float4*)(x + (size_t)o * IN_DIM + sub * 4);
        const float* W1o = W1 + (size_t)o * MID_DIM * IN_DIM;

        #pragma unroll 4
        for (int i = 0; i < 32; ++i) {
            const int row = w * 64 + 2 * i + rh;
            float4 wv = *(const float4*)(W1o + (size_t)row * IN_DIM + sub * 4);
            float acc = wv.x * xv.x + wv.y * xv.y + wv.z * xv.z + wv.w * xv.w;
            acc += __shfl_xor(acc, 16, 32);
            acc += __shfl_xor(acc,  8, 32);
            acc += __shfl_xor(acc,  4, 32);
            acc += __shfl_xor(acc,  2, 32);
            acc += __shfl_xor(acc,  1, 32);
            if (sub == 0)
                s_y1[row] = acc + b1[(size_t)o * MID_DIM + row];
        }
    }
    __syncthreads();

    // ----- Layer 2: y2[row] = sigmoid(dot(y1, W2[o,row,:]) + b2[o,row])
    // 1 row (1 KB) per iteration, 64 lanes x float4 -> contiguous 1 KB/load.
    {
        const float4 yv = *(const float4*)(s_y1 + l * 4);
        const float* W2o = W2 + (size_t)o * MID_DIM * MID_DIM;

        #pragma unroll 4
        for (int i = 0; i < 64; ++i) {
            const int row = w * 64 + i;
            float4 wv = *(const float4*)(W2o + (size_t)row * MID_DIM + l * 4);
            float acc = wv.x * yv.x + wv.y * yv.y + wv.z * yv.z + wv.w * yv.w;
            acc += __shfl_xor(acc, 32, 64);
            acc += __shfl_xor(acc, 16, 64);
            acc += __shfl_xor(acc,  8, 64);
            acc += __shfl_xor(acc,  4, 64);
            acc += __shfl_xor(acc,  2, 64);
            acc += __shfl_xor(acc,  1, 64);
            if (l == 0) {
                float z = acc + b2[(size_t)o * MID_DIM + row];
                s_y2[row] = 1.0f / (1.0f + expf(-z));
            }
        }
    }
    __syncthreads();

    // ----- Layer 3: out[o] = sigmoid(dot(y2, W3[o,0,:]) + b3[o]) — wave 0 only
    if (w == 0) {
        const float4 yv = *(const float4*)(s_y2 + l * 4);
        const float4 wv = *(const float4*)(W3 + (size_t)o * MID_DIM + l * 4);
        float acc = wv.x * yv.x + wv.y * yv.y + wv.z * yv.z + wv.w * yv.w;
        acc += __shfl_xor(acc, 32, 64);
        acc += __shfl_xor(acc, 16, 64);
        acc += __shfl_xor(acc,  8, 64);
        acc += __shfl_xor(acc,  4, 64);
        acc += __shfl_xor(acc,  2, 64);
        acc += __shfl_xor(acc,  1, 64);
        if (l == 0) {
            float z = acc + b3[o];
            out[o] = 1.0f / (1.0f + expf(-z));
        }
    }
}

extern "C" void kernel_launch(void* const* d_in, const int* in_sizes, int n_in,
                              void* d_out, int out_size, void* d_ws, size_t ws_size,
                              hipStream_t stream) {
    const float* x  = (const float*)d_in[0];
    const float* W1 = (const float*)d_in[1];
    const float* b1 = (const float*)d_in[2];
    const float* W2 = (const float*)d_in[3];
    const float* b2 = (const float*)d_in[4];
    const float* W3 = (const float*)d_in[5];
    const float* b3 = (const float*)d_in[6];
    float* out = (float*)d_out;

    mlp_grouped_kernel<<<N_OBJ, 256, 0, stream>>>(x, W1, b1, W2, b2, W3, b3, out);
}

// Round 3
// 802.658 us; speedup vs baseline: 1.0451x; 1.0411x over previous
//
#include <hip/hip_runtime.h>
#include <math.h>

// Problem: per-object 3-layer MLP (grouped GEMV).
//   N_OBJ=2048, IN_DIM=128, MID_DIM=256, OUT_DIM=1
// ~770 MB of weights streamed exactly once -> memory-bound, kernel roofline
// ~122 us @ 6.3 TB/s. NOTE: the harness's dur_us includes ~666 us of 2.1 GB
// re-poison fills (rocprof: fillBufferAligned @ 333 us each); our kernel is
// the remaining ~170 us. This version deepens the load pipeline:
//  - rolling 8-deep register prefetch (layer 2), 4-deep (layer 1)
//  - W2/W3 prefetch issued BEFORE the barrier that gates their consumption
//  - nontemporal loads for read-once weight streams (via native ext-vector:
//    __builtin_nontemporal_load rejects HIP_vector_type classes)
//  - launch_bounds(256,4): 128-VGPR cap, room for prefetch regs, no spill

#define N_OBJ   2048
#define IN_DIM  128
#define MID_DIM 256

using f4 = __attribute__((ext_vector_type(4))) float;   // native vector (nt-load OK)

__global__ __launch_bounds__(256, 4) void mlp_grouped_kernel(
    const float* __restrict__ x,   // [O, 128]
    const float* __restrict__ W1,  // [O, 256, 128]
    const float* __restrict__ b1,  // [O, 256]
    const float* __restrict__ W2,  // [O, 256, 256]
    const float* __restrict__ b2,  // [O, 256]
    const float* __restrict__ W3,  // [O, 1, 256]
    const float* __restrict__ b3,  // [O, 1]
    float* __restrict__ out)       // [O]
{
    const int o = blockIdx.x;
    const int t = threadIdx.x;
    const int w = t >> 6;   // wave id 0..3
    const int l = t & 63;   // lane id

    __shared__ __align__(16) float s_y1[MID_DIM];
    __shared__ __align__(16) float s_y2[MID_DIM];
    __shared__ float s_b1[MID_DIM];
    __shared__ float s_b2[MID_DIM];

    // Coalesced bias staging (1 float/thread; same-wave producer/consumer).
    s_b1[t] = b1[(size_t)o * MID_DIM + t];
    s_b2[t] = b2[(size_t)o * MID_DIM + t];

    // ----- Layer 1: y1[row] = dot(x, W1[o,row,:]) + b1[o,row]  (NO activation)
    // 2 rows per wave-iteration: lanes 0..31 -> row 2i, lanes 32..63 -> 2i+1.
    // Rolling 4-deep prefetch; every load instruction covers contiguous 1 KB.
    {
        const int sub = l & 31;   // float4 slot within the row
        const int rh  = l >> 5;   // which of the two rows
        const f4 xv = *(const f4*)(x + (size_t)o * IN_DIM + sub * 4);
        const float* W1o = W1 + (size_t)o * MID_DIM * IN_DIM;

        f4 pf[4];
        #pragma unroll
        for (int k = 0; k < 4; ++k) {
            const int row = w * 64 + 2 * k + rh;
            pf[k] = __builtin_nontemporal_load(
                (const f4*)(W1o + (size_t)row * IN_DIM) + sub);
        }

        for (int ii = 0; ii < 8; ++ii) {          // 8 chunks x 4 iters = 32
            #pragma unroll
            for (int k = 0; k < 4; ++k) {
                f4 wv = pf[k];
                const int ni = (ii + 1) * 4 + k;  // next iteration index
                if (ni < 32) {
                    const int nrow = w * 64 + 2 * ni + rh;
                    pf[k] = __builtin_nontemporal_load(
                        (const f4*)(W1o + (size_t)nrow * IN_DIM) + sub);
                }
                const int i = ii * 4 + k;
                const int row = w * 64 + 2 * i + rh;
                float acc = wv[0] * xv[0] + wv[1] * xv[1]
                          + wv[2] * xv[2] + wv[3] * xv[3];
                acc += __shfl_xor(acc, 16, 32);
                acc += __shfl_xor(acc,  8, 32);
                acc += __shfl_xor(acc,  4, 32);
                acc += __shfl_xor(acc,  2, 32);
                acc += __shfl_xor(acc,  1, 32);
                if (sub == 0)
                    s_y1[row] = acc + s_b1[row];
            }
        }
    }

    // Prefetch the first 8 W2 rows for this wave BEFORE the barrier:
    // addresses are independent of y1, so HBM latency hides under the
    // barrier + LDS reads.
    const float* W2o = W2 + (size_t)o * MID_DIM * MID_DIM;
    f4 pf2[8];
    #pragma unroll
    for (int k = 0; k < 8; ++k)
        pf2[k] = __builtin_nontemporal_load(
            (const f4*)(W2o + (size_t)(w * 64 + k) * MID_DIM) + l);

    __syncthreads();

    // ----- Layer 2: y2[row] = sigmoid(dot(y1, W2[o,row,:]) + b2[o,row])
    // 1 row (1 KB) per iteration, 64 lanes x float4; rolling 8-deep prefetch.
    {
        const f4 yv = *(const f4*)(s_y1 + l * 4);

        for (int ii = 0; ii < 8; ++ii) {          // 8 chunks x 8 iters = 64
            #pragma unroll
            for (int k = 0; k < 8; ++k) {
                f4 wv = pf2[k];
                const int ni = (ii + 1) * 8 + k;  // next iteration index
                if (ni < 64) {
                    pf2[k] = __builtin_nontemporal_load(
                        (const f4*)(W2o + (size_t)(w * 64 + ni) * MID_DIM) + l);
                }
                const int row = w * 64 + ii * 8 + k;
                float acc = wv[0] * yv[0] + wv[1] * yv[1]
                          + wv[2] * yv[2] + wv[3] * yv[3];
                acc += __shfl_xor(acc, 32, 64);
                acc += __shfl_xor(acc, 16, 64);
                acc += __shfl_xor(acc,  8, 64);
                acc += __shfl_xor(acc,  4, 64);
                acc += __shfl_xor(acc,  2, 64);
                acc += __shfl_xor(acc,  1, 64);
                if (l == 0) {
                    float z = acc + s_b2[row];
                    s_y2[row] = 1.0f / (1.0f + expf(-z));
                }
            }
        }
    }

    // Wave 0 prefetches its W3 row before barrier 2 (independent of y2).
    f4 w3v;
    if (w == 0)
        w3v = __builtin_nontemporal_load((const f4*)(W3 + (size_t)o * MID_DIM) + l);

    __syncthreads();

    // ----- Layer 3: out[o] = sigmoid(dot(y2, W3[o,0,:]) + b3[o]) — wave 0 only
    if (w == 0) {
        const f4 yv = *(const f4*)(s_y2 + l * 4);
        float acc = w3v[0] * yv[0] + w3v[1] * yv[1]
                  + w3v[2] * yv[2] + w3v[3] * yv[3];
        acc += __shfl_xor(acc, 32, 64);
        acc += __shfl_xor(acc, 16, 64);
        acc += __shfl_xor(acc,  8, 64);
        acc += __shfl_xor(acc,  4, 64);
        acc += __shfl_xor(acc,  2, 64);
        acc += __shfl_xor(acc,  1, 64);
        if (l == 0) {
            float z = acc + b3[o];
            out[o] = 1.0f / (1.0f + expf(-z));
        }
    }
}

extern "C" void kernel_launch(void* const* d_in, const int* in_sizes, int n_in,
                              void* d_out, int out_size, void* d_ws, size_t ws_size,
                              hipStream_t stream) {
    const float* x  = (const float*)d_in[0];
    const float* W1 = (const float*)d_in[1];
    const float* b1 = (const float*)d_in[2];
    const float* W2 = (const float*)d_in[3];
    const float* b2 = (const float*)d_in[4];
    const float* W3 = (const float*)d_in[5];
    const float* b3 = (const float*)d_in[6];
    float* out = (float*)d_out;

    mlp_grouped_kernel<<<N_OBJ, 256, 0, stream>>>(x, W1, b1, W2, b2, W3, b3, out);
}